// Round 1
// 523.851 us; speedup vs baseline: 1.0154x; 1.0154x over previous
//
#include <hip/hip_runtime.h>

// MaxPool2d 2x2 stride 1 VALID, NCHW fp32.
// In:  (16, 96, 224, 224)  Out: (16, 96, 223, 223)
//
// Strip-mined layout: each thread owns a 4-wide x 8-row output strip of one
// channel. It loads 9 input rows (aligned dwordx4 + one dword each) and keeps
// the previous row in registers, so each input row is loaded ONCE per strip
// (vs 2x in the flat mapping), and every vector load is 16B-aligned
// (input offsets nc*50176 + h*224 + 4*cg are multiples of 4 floats).
// Stores are unaligned (223-wide rows) -- the cheap side: 1 store per 2 loads.
//
// Jobs: 1536 channels * 28 row-strips * 56 col-groups = 2,408,448 = 9408 * 256
// -> grid packs exactly, no bounds check.

#define W_IN    224
#define HW_IN   (224 * 224)
#define W_OUT   223
#define H_OUT   223
#define HW_OUT  (223 * 223)
#define CGROUPS 56   // ceil(223 / 4)  (last group produces 3 outputs)
#define RSTRIPS 28   // ceil(223 / 8)  (last strip produces 7 output rows)

typedef float f4a __attribute__((ext_vector_type(4)));              // 16B-aligned
typedef float f4u __attribute__((ext_vector_type(4), aligned(4)));  // dword-aligned

__global__ __launch_bounds__(256) void maxpool2x2_s1_strip8(
    const float* __restrict__ in, float* __restrict__ out) {
  int job = blockIdx.x * 256 + threadIdx.x;
  int cg  = job % CGROUPS;             // column group (fast-varying -> coalesced)
  int t   = job / CGROUPS;
  int rs  = t % RSTRIPS;               // row strip
  int nc  = t / RSTRIPS;               // n*96 + c

  int w  = cg * 4;
  int h0 = rs * 8;
  int nrows   = (rs == RSTRIPS - 1) ? 7 : 8;  // output rows in this strip
  bool tailc  = (cg == CGROUPS - 1);          // w=220: outputs 220..222 need cols 220..223 only

  const float* p = in  + (size_t)nc * HW_IN  + (size_t)h0 * W_IN  + w;
  float*       q = out + (size_t)nc * HW_OUT + (size_t)h0 * W_OUT + w;

  // Top row of the strip.
  f4a a = *(const f4a*)p;
  float a4 = tailc ? a.w : p[4];   // masked load: no OOB read at row end

  #pragma unroll 4
  for (int r = 0; r < nrows; ++r) {
    p += W_IN;
    f4a b = *(const f4a*)p;                 // aligned dwordx4
    float b4 = tailc ? b.w : p[4];

    // vertical max (register reuse of previous row)
    float vx = fmaxf(a.x, b.x);
    float vy = fmaxf(a.y, b.y);
    float vz = fmaxf(a.z, b.z);
    float vw = fmaxf(a.w, b.w);
    float v4 = fmaxf(a4, b4);

    // horizontal max
    if (!tailc) {
      f4u o;
      o.x = fmaxf(vx, vy);
      o.y = fmaxf(vy, vz);
      o.z = fmaxf(vz, vw);
      o.w = fmaxf(vw, v4);
      *(f4u*)q = o;
    } else {
      q[0] = fmaxf(vx, vy);
      q[1] = fmaxf(vy, vz);
      q[2] = fmaxf(vz, vw);
    }
    q += W_OUT;

    a = b;
    a4 = b4;
  }
}

extern "C" void kernel_launch(void* const* d_in, const int* in_sizes, int n_in,
                              void* d_out, int out_size, void* d_ws, size_t ws_size,
                              hipStream_t stream) {
  const float* x = (const float*)d_in[0];
  float* out = (float*)d_out;
  const int jobs   = 16 * 96 * RSTRIPS * CGROUPS;  // 2,408,448
  const int blocks = jobs / 256;                   // 9408, exact
  maxpool2x2_s1_strip8<<<blocks, 256, 0, stream>>>(x, out);
}